// Round 3
// baseline (159.485 us; speedup 1.0000x reference)
//
#include <hip/hip_runtime.h>
#include <hip/hip_bf16.h>

#define N_ROWS 8192
#define H_DIM  1024
#define NUM_CLS 64
#define BM 128
#define BN 128
#define BK 64
#define NBLK (N_ROWS / BM)          // 64 panels
#define NPAIR (NBLK * (NBLK + 1) / 2)  // 2080 upper-triangle blocks

typedef __bf16 bf16x8 __attribute__((ext_vector_type(8)));
typedef float  f32x4  __attribute__((ext_vector_type(4)));

__device__ __forceinline__ float fast_exp2(float x) {
    float r;
    asm("v_exp_f32 %0, %1" : "=v"(r) : "v"(x));
    return r;
}

__device__ __forceinline__ void async_copy16(void* lds, const void* g) {
    __builtin_amdgcn_global_load_lds(
        (const __attribute__((address_space(1))) void*)g,
        (__attribute__((address_space(3))) void*)lds, 16, 0, 0);
}

// ---------------- Kernel 1: row-normalize fp32 -> bf16 ----------------
__global__ __launch_bounds__(256) void norm_kernel(const float* __restrict__ in,
                                                   ushort* __restrict__ out) {
    const int row = blockIdx.x, tid = threadIdx.x;
    const float4 v = reinterpret_cast<const float4*>(in + (size_t)row * H_DIM)[tid];
    float ss = v.x * v.x + v.y * v.y + v.z * v.z + v.w * v.w;
#pragma unroll
    for (int d = 1; d < 64; d <<= 1) ss += __shfl_xor(ss, d, 64);
    __shared__ float sred[4];
    const int lane = tid & 63, wid = tid >> 6;
    if (lane == 0) sred[wid] = ss;
    __syncthreads();
    const float tot = sred[0] + sred[1] + sred[2] + sred[3];
    const float inv = 1.0f / fmaxf(sqrtf(tot), 1e-12f);
    __hip_bfloat16 o0 = __float2bfloat16(v.x * inv);
    __hip_bfloat16 o1 = __float2bfloat16(v.y * inv);
    __hip_bfloat16 o2 = __float2bfloat16(v.z * inv);
    __hip_bfloat16 o3 = __float2bfloat16(v.w * inv);
    ushort4 o;
    o.x = *reinterpret_cast<ushort*>(&o0);
    o.y = *reinterpret_cast<ushort*>(&o1);
    o.z = *reinterpret_cast<ushort*>(&o2);
    o.w = *reinterpret_cast<ushort*>(&o3);
    reinterpret_cast<ushort4*>(out + (size_t)row * H_DIM)[tid] = o;
}

// ---- Kernel 2: symmetric fused Gram + exp + masked row/col partials ----
// Pipelined double-buffer: STAGE(t+1) issued before compute(t); counted
// vmcnt(8) (never 0 in loop); raw s_barrier; compiler-inserted lgkmcnt
// before MFMA guarantees reads-done-before-barrier#2.
// grid = NPAIR (upper-triangle 128x128 blocks); block = 256 (4 waves, 2x2)
__global__ __launch_bounds__(256, 2)
void simloss_kernel(const ushort* __restrict__ xb, const int* __restrict__ labels,
                    float* __restrict__ ppos, float* __restrict__ pall) {
    __shared__ __align__(16) ushort As[2][BM * BK];
    __shared__ __align__(16) ushort Bs[2][BN * BK];

    // decode linear bid -> (I, J) with I <= J, row-major over the triangle
    int t = blockIdx.x, I = 0;
    while (t >= NBLK - I) { t -= NBLK - I; ++I; }
    const int J = I + t;
    const bool diag = (I == J);
    const int row0 = I * BM, col0 = J * BN;

    const int tid  = threadIdx.x;
    const int lane = tid & 63;
    const int wid  = tid >> 6;
    const int wr = wid >> 1, wc = wid & 1;
    const int l15 = lane & 15, lq = lane >> 4;

    // staging geometry: segment = 1024B = 8 rows x 64 bf16; 16 segs per tile
    const int srow  = lane >> 3;   // row within segment (0..7)
    const int pslot = lane & 7;    // physical 16B slot within row

    // labels for the 16 rows this lane accumulates (issued before staging;
    // older than all loop loads so counted vmcnt stays conservative)
    int lab_r[16];
#pragma unroll
    for (int m = 0; m < 4; ++m)
#pragma unroll
        for (int r = 0; r < 4; ++r)
            lab_r[m * 4 + r] = labels[row0 + wr * 64 + m * 16 + lq * 4 + r];

    f32x4 acc[4][4];
#pragma unroll
    for (int m = 0; m < 4; ++m)
#pragma unroll
        for (int n = 0; n < 4; ++n) acc[m][n] = (f32x4){0.f, 0.f, 0.f, 0.f};

#define STAGE(buf, k0)                                                          \
    do {                                                                        \
        _Pragma("unroll")                                                       \
        for (int i = 0; i < 4; ++i) {                                           \
            const int seg = wid * 4 + i;                                        \
            const int row = seg * 8 + srow;                                     \
            const int lslot = pslot ^ (row & 7); /* pre-swizzled src, rule 21 */\
            async_copy16(&As[buf][seg * 512],                                   \
                         &xb[(size_t)(row0 + row) * H_DIM + (k0) + lslot * 8]); \
            async_copy16(&Bs[buf][seg * 512],                                   \
                         &xb[(size_t)(col0 + row) * H_DIM + (k0) + lslot * 8]); \
        }                                                                       \
    } while (0)

    // prologue: stage K-tile 0 into buf 0
    STAGE(0, 0);

    int cur = 0;
    for (int k0 = 0; k0 < H_DIM; k0 += BK) {
        const bool has_next = (k0 + BK < H_DIM);
        if (has_next) {
            STAGE(cur ^ 1, k0 + BK);                     // 8 loads, stay in flight
            asm volatile("s_waitcnt vmcnt(8)" ::: "memory");  // drain tile t only
        } else {
            asm volatile("s_waitcnt vmcnt(0)" ::: "memory");
        }
        __builtin_amdgcn_s_barrier();                    // buf[cur] ready for all
        asm volatile("" ::: "memory");                   // no LDS-read hoist above
#pragma unroll
        for (int kh = 0; kh < 2; ++kh) {
            bf16x8 af[4], bfv[4];
#pragma unroll
            for (int m = 0; m < 4; ++m) {
                const int row = wr * 64 + m * 16 + l15;
                const int ps = (kh * 4 + lq) ^ (row & 7);
                af[m] = *reinterpret_cast<const bf16x8*>(&As[cur][row * 64 + ps * 8]);
            }
#pragma unroll
            for (int n = 0; n < 4; ++n) {
                const int row = wc * 64 + n * 16 + l15;
                const int ps = (kh * 4 + lq) ^ (row & 7);
                bfv[n] = *reinterpret_cast<const bf16x8*>(&Bs[cur][row * 64 + ps * 8]);
            }
            __builtin_amdgcn_s_setprio(1);
#pragma unroll
            for (int m = 0; m < 4; ++m)
#pragma unroll
                for (int n = 0; n < 4; ++n)
                    acc[m][n] = __builtin_amdgcn_mfma_f32_16x16x32_bf16(
                        af[m], bfv[n], acc[m][n], 0, 0, 0);
            __builtin_amdgcn_s_setprio(0);
        }
        asm volatile("" ::: "memory");                   // no LDS-read sink below
        __builtin_amdgcn_s_barrier();                    // all reads of buf[cur] done
        cur ^= 1;
    }
#undef STAGE

    // ---- epilogue: exp + masked row sums AND column sums ----
    float rs_pos[16], rs_all[16];
#pragma unroll
    for (int i = 0; i < 16; ++i) { rs_pos[i] = 0.f; rs_all[i] = 0.f; }
    float cs_pos[4], cs_all[4];
#pragma unroll
    for (int n = 0; n < 4; ++n) { cs_pos[n] = 0.f; cs_all[n] = 0.f; }

#pragma unroll
    for (int n = 0; n < 4; ++n) {
        const int colg = col0 + wc * 64 + n * 16 + l15;
        const int lab_c = labels[colg];
#pragma unroll
        for (int m = 0; m < 4; ++m) {
#pragma unroll
            for (int r = 0; r < 4; ++r) {
                const int rowg = row0 + wr * 64 + m * 16 + lq * 4 + r;
                const float e = fast_exp2(acc[m][n][r] * 14.4269504088896340736f);
                const bool self = (rowg == colg);       // only possible when diag
                const bool pos  = (lab_c == lab_r[m * 4 + r]) && !self;
                const float ea = self ? 0.f : e;
                const float ep = pos ? e : 0.f;
                rs_all[m * 4 + r] += ea;
                rs_pos[m * 4 + r] += ep;
                cs_all[n] += ea;
                cs_pos[n] += ep;
            }
        }
    }

    // row partials: reduce across l15 (16-lane groups)
#pragma unroll
    for (int i = 0; i < 16; ++i) {
#pragma unroll
        for (int d = 1; d < 16; d <<= 1) {
            rs_pos[i] += __shfl_xor(rs_pos[i], d, 64);
            rs_all[i] += __shfl_xor(rs_all[i], d, 64);
        }
    }
    // col partials: reduce across lq (lanes differing in bits 4,5)
#pragma unroll
    for (int n = 0; n < 4; ++n) {
#pragma unroll
        for (int d = 16; d < 64; d <<= 1) {
            cs_pos[n] += __shfl_xor(cs_pos[n], d, 64);
            cs_all[n] += __shfl_xor(cs_all[n], d, 64);
        }
    }

    // cross-wave combine via LDS scratch aliased onto As (4 KB)
    __syncthreads();                       // all LDS fragment reads done
    float* sc = (float*)&As[0][0];
    float* rowpos = sc;                    // [2][128] indexed [wc][localrow]
    float* rowall = sc + 256;
    float* colpos = sc + 512;              // [2][128] indexed [wr][localcol]
    float* colall = sc + 768;
    if (l15 == 0) {
#pragma unroll
        for (int i = 0; i < 16; ++i) {
            const int m = i >> 2, r = i & 3;
            const int lr = wr * 64 + m * 16 + lq * 4 + r;
            rowpos[wc * 128 + lr] = rs_pos[i];
            rowall[wc * 128 + lr] = rs_all[i];
        }
    }
    if (lq == 0 && !diag) {
#pragma unroll
        for (int n = 0; n < 4; ++n) {
            const int lc = wc * 64 + n * 16 + l15;
            colpos[wr * 128 + lc] = cs_pos[n];
            colall[wr * 128 + lc] = cs_all[n];
        }
    }
    __syncthreads();

    // partial-slot scheme: row-side -> slot J, col-side -> slot I.
    // Every (slot s, row i) written exactly once across the triangle.
    if (tid < 128) {
        const float rp = rowpos[tid] + rowpos[128 + tid];
        const float ra = rowall[tid] + rowall[128 + tid];
        ppos[(size_t)J * N_ROWS + row0 + tid] = rp;
        pall[(size_t)J * N_ROWS + row0 + tid] = ra;
    } else if (!diag) {
        const int t2 = tid - 128;
        const float cp = colpos[t2] + colpos[128 + t2];
        const float ca = colall[t2] + colall[128 + t2];
        ppos[(size_t)I * N_ROWS + col0 + t2] = cp;
        pall[(size_t)I * N_ROWS + col0 + t2] = ca;
    }
}

// ---------------- Kernel 3a: per-row loss, per-block partial sums ----------------
__global__ __launch_bounds__(256)
void finalize1_kernel(const int* __restrict__ labels, const float* __restrict__ ppos,
                      const float* __restrict__ pall, float* __restrict__ bsum,
                      int* __restrict__ bcnt) {
    __shared__ int hist[NUM_CLS];
    __shared__ float sred[4];
    __shared__ int scnt[4];
    const int tid = threadIdx.x;
    if (tid < NUM_CLS) hist[tid] = 0;
    __syncthreads();
    for (int i = tid; i < N_ROWS; i += 256) atomicAdd(&hist[labels[i]], 1);
    __syncthreads();

    float lsum = 0.f;
    int vcnt = 0;
    if (tid < 128) {
        const int i = blockIdx.x * 128 + tid;
        float p = 0.f, a = 0.f;
#pragma unroll
        for (int s = 0; s < NBLK; ++s) {
            p += ppos[(size_t)s * N_ROWS + i];
            a += pall[(size_t)s * N_ROWS + i];
        }
        const int cnt = hist[labels[i]] - 1;
        if (cnt > 0) {
            lsum = logf(a) - logf(p) + logf((float)cnt);
            vcnt = 1;
        }
    }
    const int lane = tid & 63, wid = tid >> 6;
#pragma unroll
    for (int d = 1; d < 64; d <<= 1) {
        lsum += __shfl_xor(lsum, d, 64);
        vcnt += __shfl_xor(vcnt, d, 64);
    }
    if (lane == 0) { sred[wid] = lsum; scnt[wid] = vcnt; }
    __syncthreads();
    if (tid == 0) {
        bsum[blockIdx.x] = sred[0] + sred[1] + sred[2] + sred[3];
        bcnt[blockIdx.x] = scnt[0] + scnt[1] + scnt[2] + scnt[3];
    }
}

// ---------------- Kernel 3b: final scalar ----------------
__global__ __launch_bounds__(64)
void finalize2_kernel(const float* __restrict__ bsum, const int* __restrict__ bcnt,
                      float* __restrict__ out) {
    const int tid = threadIdx.x;
    float s = bsum[tid];
    int   c = bcnt[tid];
#pragma unroll
    for (int d = 1; d < 64; d <<= 1) {
        s += __shfl_xor(s, d, 64);
        c += __shfl_xor(c, d, 64);
    }
    if (tid == 0) out[0] = s / (float)c;
}

extern "C" void kernel_launch(void* const* d_in, const int* in_sizes, int n_in,
                              void* d_out, int out_size, void* d_ws, size_t ws_size,
                              hipStream_t stream) {
    const float* emb   = (const float*)d_in[0];
    const int* labels  = (const int*)d_in[1];
    float* out         = (float*)d_out;
    char* ws           = (char*)d_ws;

    ushort* xb  = (ushort*)ws;                                   // 16 MB bf16 normalized
    float* ppos = (float*)(ws + (size_t)N_ROWS * H_DIM * 2);     // NBLK*N floats (2 MB)
    float* pall = ppos + (size_t)NBLK * N_ROWS;                  // NBLK*N floats (2 MB)
    float* bsum = pall + (size_t)NBLK * N_ROWS;                  // 64 floats
    int*   bcnt = (int*)(bsum + NBLK);                           // 64 ints

    norm_kernel<<<N_ROWS, 256, 0, stream>>>(emb, xb);
    simloss_kernel<<<NPAIR, 256, 0, stream>>>(xb, labels, ppos, pall);
    finalize1_kernel<<<NBLK, 256, 0, stream>>>(labels, ppos, pall, bsum, bcnt);
    finalize2_kernel<<<1, 64, 0, stream>>>(bsum, bcnt, out);
}

// Round 4
// 141.621 us; speedup vs baseline: 1.1261x; 1.1261x over previous
//
#include <hip/hip_runtime.h>
#include <hip/hip_bf16.h>

#define N_ROWS 8192
#define H_DIM  1024
#define NUM_CLS 64
#define BT 256                          // tile: 256x256
#define BK 32                           // K-step per group (= one MFMA K)
#define NP (N_ROWS / BT)                // 32 panels
#define NPAIR (NP * (NP + 1) / 2)       // 528 upper-triangle blocks
#define NG (H_DIM / BK)                 // 32 K-groups

typedef __bf16 bf16x8 __attribute__((ext_vector_type(8)));
typedef float  f32x4  __attribute__((ext_vector_type(4)));

__device__ __forceinline__ float fast_exp2(float x) {
    float r;
    asm("v_exp_f32 %0, %1" : "=v"(r) : "v"(x));
    return r;
}

__device__ __forceinline__ void async_copy16(void* lds, const void* g) {
    __builtin_amdgcn_global_load_lds(
        (const __attribute__((address_space(1))) void*)g,
        (__attribute__((address_space(3))) void*)lds, 16, 0, 0);
}

// ---------------- Kernel 1: row-normalize fp32 -> bf16 ----------------
__global__ __launch_bounds__(256) void norm_kernel(const float* __restrict__ in,
                                                   ushort* __restrict__ out) {
    const int row = blockIdx.x, tid = threadIdx.x;
    const float4 v = reinterpret_cast<const float4*>(in + (size_t)row * H_DIM)[tid];
    float ss = v.x * v.x + v.y * v.y + v.z * v.z + v.w * v.w;
#pragma unroll
    for (int d = 1; d < 64; d <<= 1) ss += __shfl_xor(ss, d, 64);
    __shared__ float sred[4];
    const int lane = tid & 63, wid = tid >> 6;
    if (lane == 0) sred[wid] = ss;
    __syncthreads();
    const float tot = sred[0] + sred[1] + sred[2] + sred[3];
    const float inv = 1.0f / fmaxf(sqrtf(tot), 1e-12f);
    __hip_bfloat16 o0 = __float2bfloat16(v.x * inv);
    __hip_bfloat16 o1 = __float2bfloat16(v.y * inv);
    __hip_bfloat16 o2 = __float2bfloat16(v.z * inv);
    __hip_bfloat16 o3 = __float2bfloat16(v.w * inv);
    ushort4 o;
    o.x = *reinterpret_cast<ushort*>(&o0);
    o.y = *reinterpret_cast<ushort*>(&o1);
    o.z = *reinterpret_cast<ushort*>(&o2);
    o.w = *reinterpret_cast<ushort*>(&o3);
    reinterpret_cast<ushort4*>(out + (size_t)row * H_DIM)[tid] = o;
}

// ---- Kernel 2: symmetric fused Gram + exp + masked row/col partials ----
// 256x256 tile, 512 threads (8 waves 2x4), 4-slot LDS ring (128 KB),
// 1 raw barrier per K-group, counted vmcnt (10/8/4/0), setprio on MFMA.
__global__ __launch_bounds__(512, 2)
void simloss_kernel(const ushort* __restrict__ xb, const int* __restrict__ labels,
                    float* __restrict__ ppos, float* __restrict__ pall) {
    // [slot][A=0/B=1][256 rows x 32 cols bf16] : 4*2*16KB = 128 KB
    __shared__ __align__(16) ushort SL[4 * 2 * (BT * BK)];

    // XCD-aware bijective swizzle (528 = 8*66)
    const int bid = (blockIdx.x & 7) * (NPAIR / 8) + (blockIdx.x >> 3);
    // decode -> (I, J), I <= J
    int t = bid, I = 0;
    while (t >= NP - I) { t -= NP - I; ++I; }
    const int J = I + t;
    const bool diag = (I == J);
    const int row0 = I * BT, col0 = J * BT;

    const int tid  = threadIdx.x;
    const int lane = tid & 63;
    const int wid  = tid >> 6;        // 0..7
    const int wr = wid >> 2;          // 0..1  (M wave row)
    const int wc = wid & 3;           // 0..3  (N wave col)
    const int l15 = lane & 15, lq = lane >> 4;

    // fragment LDS addressing (ushort units); pslot = lq ^ ((row>>1)&3),
    // row components wr*128/ mf*16 / wc*64 / nf*16 are 0 mod 4 after >>1.
    const int pslot8 = (lq ^ ((l15 >> 1) & 3)) * 8;
    const int aoff = (wr * 128 + l15) * 32 + pslot8;   // + mf*512
    const int boff = (wc * 64 + l15) * 32 + pslot8;    // + nf*512

    // STAGE one 16KB A-or-B tile for K-tile kt into slot: 2 issues/thread.
    // LDS dest linear (wave-uniform base, HW adds lane*16); source column
    // pre-swizzled with the same involution the ds_read applies (rule #21).
#define STAGE(slot, ab, baserow, k0)                                           \
    do {                                                                       \
        _Pragma("unroll")                                                      \
        for (int q = 0; q < 2; ++q) {                                          \
            const int seg = wid * 2 + q;              /* 0..15: 16 rows each */\
            const int row = seg * 16 + (lane >> 2);                            \
            const int ls  = (lane & 3) ^ ((row >> 1) & 3);                     \
            async_copy16(&SL[(slot) * 16384 + (ab) * 8192 + seg * 512],        \
                         &xb[(size_t)((baserow) + row) * H_DIM + (k0) + ls * 8]); \
        }                                                                      \
    } while (0)

    f32x4 acc[8][4];
#pragma unroll
    for (int m = 0; m < 8; ++m)
#pragma unroll
        for (int n = 0; n < 4; ++n) acc[m][n] = (f32x4){0.f, 0.f, 0.f, 0.f};

    // prologue: stage K-tiles 0,1,2 into slots 0,1,2 (12 issues/thread)
    STAGE(0, 0, row0, 0);  STAGE(0, 1, col0, 0);
    STAGE(1, 0, row0, 32); STAGE(1, 1, col0, 32);
    STAGE(2, 0, row0, 64); STAGE(2, 1, col0, 64);

    for (int g = 0; g < NG; ++g) {
        const int slot = g & 3;
        if (g + 3 < NG) STAGE((g + 3) & 3, 0, row0, (g + 3) * BK);  // A(g+3)
        // drain exactly K-tile g's 4 issues (A+B); keep the rest in flight
        if (g < NG - 3)       asm volatile("s_waitcnt vmcnt(10)" ::: "memory");
        else if (g == NG - 3) asm volatile("s_waitcnt vmcnt(8)"  ::: "memory");
        else if (g == NG - 2) asm volatile("s_waitcnt vmcnt(4)"  ::: "memory");
        else                  asm volatile("s_waitcnt vmcnt(0)"  ::: "memory");
        __builtin_amdgcn_s_barrier();          // all waves' tile-g loads landed
        asm volatile("" ::: "memory");

        const ushort* Ab = &SL[slot * 16384];
        const ushort* Bb = &SL[slot * 16384 + 8192];
        bf16x8 bfv[4];
#pragma unroll
        for (int nf = 0; nf < 4; ++nf)
            bfv[nf] = *reinterpret_cast<const bf16x8*>(&Bb[boff + nf * 512]);
#pragma unroll
        for (int qm = 0; qm < 2; ++qm) {
            bf16x8 af[4];
#pragma unroll
            for (int i = 0; i < 4; ++i)
                af[i] = *reinterpret_cast<const bf16x8*>(
                    &Ab[aoff + (qm * 4 + i) * 512]);
            __builtin_amdgcn_s_setprio(1);
#pragma unroll
            for (int i = 0; i < 4; ++i)
#pragma unroll
                for (int nf = 0; nf < 4; ++nf)
                    acc[qm * 4 + i][nf] = __builtin_amdgcn_mfma_f32_16x16x32_bf16(
                        af[i], bfv[nf], acc[qm * 4 + i][nf], 0, 0, 0);
            __builtin_amdgcn_s_setprio(0);
            if (qm == 0 && g + 3 < NG) STAGE((g + 3) & 3, 1, col0, (g + 3) * BK);
        }
    }
#undef STAGE
    __syncthreads();   // all compute done; SL reusable as scratch

    // ---- epilogue: exp + masked row sums (per (mf,r)) and column sums ----
    int lab_c[4];
#pragma unroll
    for (int nf = 0; nf < 4; ++nf)
        lab_c[nf] = labels[col0 + wc * 64 + nf * 16 + l15];
    float cs_p[4] = {0.f, 0.f, 0.f, 0.f}, cs_a[4] = {0.f, 0.f, 0.f, 0.f};

    float* sc = (float*)&SL[0];
    float* rowpos = sc;            // [4][256] indexed [wc][localrow]
    float* rowall = sc + 1024;
    float* colpos = sc + 2048;     // [2][256] indexed [wr][localcol]
    float* colall = sc + 2560;

#pragma unroll
    for (int mf = 0; mf < 8; ++mf) {
#pragma unroll
        for (int r = 0; r < 4; ++r) {
            const int lrow = wr * 128 + mf * 16 + lq * 4 + r;
            const int rowg = row0 + lrow;
            const int labr = labels[rowg];
            float p = 0.f, a = 0.f;
#pragma unroll
            for (int nf = 0; nf < 4; ++nf) {
                const int colg = col0 + wc * 64 + nf * 16 + l15;
                const float e = fast_exp2(acc[mf][nf][r] * 14.4269504088896340736f);
                const bool self = (rowg == colg);      // only when diag
                const float ea = self ? 0.f : e;
                const float ep = (!self && labr == lab_c[nf]) ? e : 0.f;
                a += ea; p += ep;
                cs_a[nf] += ea; cs_p[nf] += ep;
            }
#pragma unroll
            for (int d = 1; d < 16; d <<= 1) {
                p += __shfl_xor(p, d, 64);
                a += __shfl_xor(a, d, 64);
            }
            if (l15 == 0) {
                rowpos[wc * 256 + lrow] = p;
                rowall[wc * 256 + lrow] = a;
            }
        }
    }
#pragma unroll
    for (int nf = 0; nf < 4; ++nf) {
#pragma unroll
        for (int d = 16; d < 64; d <<= 1) {
            cs_p[nf] += __shfl_xor(cs_p[nf], d, 64);
            cs_a[nf] += __shfl_xor(cs_a[nf], d, 64);
        }
    }
    if (lq == 0) {
#pragma unroll
        for (int nf = 0; nf < 4; ++nf) {
            const int lcol = wc * 64 + nf * 16 + l15;
            colpos[wr * 256 + lcol] = cs_p[nf];
            colall[wr * 256 + lcol] = cs_a[nf];
        }
    }
    __syncthreads();

    // partial-slot scheme: row-side -> slot J, col-side -> slot I;
    // every (slot, row) pair written exactly once across the triangle.
    if (tid < 256) {
        const float rp = rowpos[tid] + rowpos[256 + tid] + rowpos[512 + tid] + rowpos[768 + tid];
        const float ra = rowall[tid] + rowall[256 + tid] + rowall[512 + tid] + rowall[768 + tid];
        ppos[(size_t)J * N_ROWS + row0 + tid] = rp;
        pall[(size_t)J * N_ROWS + row0 + tid] = ra;
    } else if (!diag) {
        const int c = tid - 256;
        const float cp = colpos[c] + colpos[256 + c];
        const float ca = colall[c] + colall[256 + c];
        ppos[(size_t)I * N_ROWS + col0 + c] = cp;
        pall[(size_t)I * N_ROWS + col0 + c] = ca;
    }
}

// ---------------- Kernel 3a: per-row loss, per-block partial sums ----------------
// grid = 32 blocks x 256 threads; block b handles rows b*256..b*256+255
__global__ __launch_bounds__(256)
void finalize1_kernel(const int* __restrict__ labels, const float* __restrict__ ppos,
                      const float* __restrict__ pall, float* __restrict__ bsum,
                      int* __restrict__ bcnt) {
    __shared__ int hist[NUM_CLS];
    __shared__ float sred[4];
    __shared__ int scnt[4];
    const int tid = threadIdx.x;
    if (tid < NUM_CLS) hist[tid] = 0;
    __syncthreads();
    for (int i = tid; i < N_ROWS; i += 256) atomicAdd(&hist[labels[i]], 1);
    __syncthreads();

    const int i = blockIdx.x * 256 + tid;
    float p = 0.f, a = 0.f;
#pragma unroll
    for (int s = 0; s < NP; ++s) {
        p += ppos[(size_t)s * N_ROWS + i];
        a += pall[(size_t)s * N_ROWS + i];
    }
    float lsum = 0.f;
    int vcnt = 0;
    const int cnt = hist[labels[i]] - 1;
    if (cnt > 0) {
        lsum = logf(a) - logf(p) + logf((float)cnt);
        vcnt = 1;
    }
    const int lane = tid & 63, wid = tid >> 6;
#pragma unroll
    for (int d = 1; d < 64; d <<= 1) {
        lsum += __shfl_xor(lsum, d, 64);
        vcnt += __shfl_xor(vcnt, d, 64);
    }
    if (lane == 0) { sred[wid] = lsum; scnt[wid] = vcnt; }
    __syncthreads();
    if (tid == 0) {
        bsum[blockIdx.x] = sred[0] + sred[1] + sred[2] + sred[3];
        bcnt[blockIdx.x] = scnt[0] + scnt[1] + scnt[2] + scnt[3];
    }
}

// ---------------- Kernel 3b: final scalar ----------------
__global__ __launch_bounds__(64)
void finalize2_kernel(const float* __restrict__ bsum, const int* __restrict__ bcnt,
                      float* __restrict__ out) {
    const int tid = threadIdx.x;
    float s = (tid < NP) ? bsum[tid] : 0.f;
    int   c = (tid < NP) ? bcnt[tid] : 0;
#pragma unroll
    for (int d = 1; d < 64; d <<= 1) {
        s += __shfl_xor(s, d, 64);
        c += __shfl_xor(c, d, 64);
    }
    if (tid == 0) out[0] = s / (float)c;
}

extern "C" void kernel_launch(void* const* d_in, const int* in_sizes, int n_in,
                              void* d_out, int out_size, void* d_ws, size_t ws_size,
                              hipStream_t stream) {
    const float* emb   = (const float*)d_in[0];
    const int* labels  = (const int*)d_in[1];
    float* out         = (float*)d_out;
    char* ws           = (char*)d_ws;

    ushort* xb  = (ushort*)ws;                                   // 16 MB bf16 normalized
    float* ppos = (float*)(ws + (size_t)N_ROWS * H_DIM * 2);     // NP*N floats (1 MB)
    float* pall = ppos + (size_t)NP * N_ROWS;                    // NP*N floats (1 MB)
    float* bsum = pall + (size_t)NP * N_ROWS;                    // 32 floats
    int*   bcnt = (int*)(bsum + NP);                             // 32 ints

    norm_kernel<<<N_ROWS, 256, 0, stream>>>(emb, xb);
    simloss_kernel<<<NPAIR, 512, 0, stream>>>(xb, labels, ppos, pall);
    finalize1_kernel<<<NP, 256, 0, stream>>>(labels, ppos, pall, bsum, bcnt);
    finalize2_kernel<<<1, 64, 0, stream>>>(bsum, bcnt, out);
}